// Round 7
// baseline (1233.802 us; speedup 1.0000x reference)
//
#include <hip/hip_runtime.h>
#include <hip/hip_bf16.h>

#define NN 10000
#define NPAD 10048   // 157 * 64
#define EE 320000
#define DD 256
#define LL 5
#define NBLK 256     // <= #CUs: all blocks resident under ANY occupancy >= 1

typedef __bf16 bf16x8 __attribute__((ext_vector_type(8)));
typedef float f32x4 __attribute__((ext_vector_type(4)));

__device__ __forceinline__ void gload_lds16(const void* g, void* l) {
    __builtin_amdgcn_global_load_lds(
        (const __attribute__((address_space(1))) void*)g,
        (__attribute__((address_space(3))) void*)l, 16, 0, 0);
}

// ---------------- global barrier (regular launch, device-scope atomics) ----------------
// bar[0]=arrive counter, bar[1]=generation. Zeroed by prep_k each launch.

__device__ __forceinline__ void gbar(int* bar, int nb) {
    __syncthreads();
    if (threadIdx.x == 0) {
        __threadfence();  // release all prior writes (agent scope: L2 writeback)
        int g = __hip_atomic_load(bar + 1, __ATOMIC_RELAXED, __HIP_MEMORY_SCOPE_AGENT);
        int a = __hip_atomic_fetch_add(bar, 1, __ATOMIC_ACQ_REL, __HIP_MEMORY_SCOPE_AGENT);
        if (a == nb - 1) {
            __hip_atomic_store(bar, 0, __ATOMIC_RELAXED, __HIP_MEMORY_SCOPE_AGENT);
            __hip_atomic_fetch_add(bar + 1, 1, __ATOMIC_RELEASE, __HIP_MEMORY_SCOPE_AGENT);
        } else {
            while (__hip_atomic_load(bar + 1, __ATOMIC_ACQUIRE, __HIP_MEMORY_SCOPE_AGENT) == g)
                __builtin_amdgcn_s_sleep(1);
        }
        __threadfence();  // acquire side: invalidate caches before reading peers' data
    }
    __syncthreads();
}

// ---------------- setup kernels ----------------

// Wt[l][j][k] = W[l][k][j], bf16 (NT layout for m-GEMM)
__global__ void transpose_wb_k(const float* __restrict__ W, __bf16* __restrict__ Wt) {
    __shared__ float t[32][33];
    int l = blockIdx.z;
    int bx = blockIdx.x * 32;
    int by = blockIdx.y * 32;
    for (int i = threadIdx.y; i < 32; i += 8)
        t[i][threadIdx.x] = W[l * 65536 + (by + i) * DD + bx + threadIdx.x];
    __syncthreads();
    for (int i = threadIdx.y; i < 32; i += 8)
        Wt[l * 65536 + (bx + i) * DD + by + threadIdx.x] = (__bf16)t[threadIdx.x][i];
}

// merged elementwise prep: gru-weight conv, x conv, pad-zero, deg-zero, barrier-zero
__global__ void prep_k(const float* __restrict__ w_ih, const float* __restrict__ w_hh,
                       const float* __restrict__ x,
                       __bf16* __restrict__ wihb, __bf16* __restrict__ whhb,
                       float* __restrict__ hb, __bf16* __restrict__ hbfA,
                       __bf16* __restrict__ hbfB, __bf16* __restrict__ mb,
                       __bf16* __restrict__ aggb, int* __restrict__ deg,
                       int* __restrict__ bar) {
    int i = blockIdx.x * blockDim.x + threadIdx.x;
    if (i < NN * DD) { float v = x[i]; hb[i] = v; hbfA[i] = (__bf16)v; }
    if (i < 768 * 256) { wihb[i] = (__bf16)w_ih[i]; whhb[i] = (__bf16)w_hh[i]; }
    if (i < (NPAD - NN) * DD) {
        hbfA[NN * DD + i] = (__bf16)0.f;
        hbfB[NN * DD + i] = (__bf16)0.f;
        mb[NN * DD + i] = (__bf16)0.f;
        aggb[NN * DD + i] = (__bf16)0.f;
    }
    if (i < NN) deg[i] = 0;
    if (i < 2) bar[i] = 0;
}

__global__ void hist_k(const int* __restrict__ dst, int* __restrict__ deg) {
    int e = blockIdx.x * blockDim.x + threadIdx.x;
    if (e < EE) atomicAdd(&deg[dst[e]], 1);
}

__global__ void scan_k(const int* __restrict__ deg, int* __restrict__ row_start,
                       int* __restrict__ cursor) {
    __shared__ int sums[1024];
    const int CH = 10;
    int t = threadIdx.x;
    int base = t * CH;
    int loc[CH];
    int s = 0;
#pragma unroll
    for (int i = 0; i < CH; i++) {
        int v = (base + i < NN) ? deg[base + i] : 0;
        loc[i] = s;
        s += v;
    }
    sums[t] = s;
    __syncthreads();
    for (int off = 1; off < 1024; off <<= 1) {
        int v = (t >= off) ? sums[t - off] : 0;
        __syncthreads();
        sums[t] += v;
        __syncthreads();
    }
    int pre = (t == 0) ? 0 : sums[t - 1];
#pragma unroll
    for (int i = 0; i < CH; i++) {
        int idx = base + i;
        if (idx < NN) {
            int v = pre + loc[i];
            row_start[idx] = v;
            cursor[idx] = v;
        }
    }
    if (t == 1023) row_start[NN] = sums[1023];
}

__global__ void fill_k(const int* __restrict__ ei, const float* __restrict__ attr,
                       int* __restrict__ cursor, int* __restrict__ ssrc,
                       float* __restrict__ sattr) {
    int e = blockIdx.x * blockDim.x + threadIdx.x;
    if (e < EE) {
        int dv = ei[EE + e];
        int p = atomicAdd(&cursor[dv], 1);
        ssrc[p] = ei[e];
        sattr[p] = attr[e];
    }
}

// ---------------- mega kernel phase helpers ----------------

// m = h @ W tile (64 nodes x 64 cols); smraw: sA 4KB @0, sB 4KB @4096
__device__ __forceinline__ void gemm_tile(int t, const __bf16* __restrict__ hbf,
                                          const __bf16* __restrict__ wt,
                                          __bf16* __restrict__ mout, char* smraw) {
    __bf16* sA = (__bf16*)smraw;
    __bf16* sB = (__bf16*)(smraw + 4096);
    int tid = threadIdx.x;
    int wave = tid >> 6, lane = tid & 63;
    int ln = lane & 15, quad = lane >> 4;
    int rowBlock = (t >> 2) * 64;
    int colBlock = (t & 3) * 64;
    int rowHalf = (wave >> 1) * 32;
    int colHalf = (wave & 1) * 32;
    int r4 = lane >> 2;
    int kb = (lane & 3) * 8;

    f32x4 acc[2][2] = {};

    for (int k0 = 0; k0 < DD; k0 += 32) {
        __syncthreads();
#pragma unroll
        for (int ii = 0; ii < 2; ii++) {
            int rg = (wave & 1) * 2 + ii;
            const __bf16* src;
            __bf16* dst;
            if (wave < 2) {
                src = hbf + (size_t)(rowBlock + rg * 16 + r4) * DD + k0 + kb;
                dst = sA + rg * 512;
            } else {
                src = wt + (size_t)(colBlock + rg * 16 + r4) * DD + k0 + kb;
                dst = sB + rg * 512;
            }
            gload_lds16(src, dst);
        }
        __syncthreads();

        bf16x8 af[2], bf[2];
#pragma unroll
        for (int i = 0; i < 2; i++)
            af[i] = *(const bf16x8*)(sA + (rowHalf + i * 16 + ln) * 32 + quad * 8);
#pragma unroll
        for (int cc = 0; cc < 2; cc++)
            bf[cc] = *(const bf16x8*)(sB + (colHalf + cc * 16 + ln) * 32 + quad * 8);
#pragma unroll
        for (int nf = 0; nf < 2; nf++)
#pragma unroll
            for (int cc = 0; cc < 2; cc++)
                acc[nf][cc] = __builtin_amdgcn_mfma_f32_16x16x32_bf16(af[nf], bf[cc], acc[nf][cc], 0, 0, 0);
    }
#pragma unroll
    for (int nf = 0; nf < 2; nf++)
#pragma unroll
        for (int r = 0; r < 4; r++) {
            int n = rowBlock + rowHalf + nf * 16 + quad * 4 + r;
#pragma unroll
            for (int cc = 0; cc < 2; cc++) {
                int d = colBlock + colHalf + cc * 16 + ln;
                mout[(size_t)n * DD + d] = (__bf16)acc[nf][cc][r];
            }
        }
}

// aggregate group of 4 nodes (one per wave); smraw: sIdx 1KB @0, sAtt 1KB @1024
__device__ __forceinline__ void agg_group(int g, const __bf16* __restrict__ m,
                                          const int* __restrict__ row_start,
                                          const int* __restrict__ ssrc,
                                          const float* __restrict__ sattr,
                                          __bf16* __restrict__ aggb, char* smraw) {
    int* sIdx = (int*)smraw;
    float* sAtt = (float*)(smraw + 1024);
    int w = threadIdx.x >> 6, lane = threadIdx.x & 63;
    int n = g * 4 + w;
    int s0 = row_start[n], s1 = row_start[n + 1];
    int half = lane >> 5;
    int c8 = (lane & 31) * 8;

    float acc[8] = {0.f, 0.f, 0.f, 0.f, 0.f, 0.f, 0.f, 0.f};

    for (int base = s0; base < s1; base += 64) {
        int cnt = min(64, s1 - base);
        if (lane < cnt) {
            sIdx[w * 64 + lane] = ssrc[base + lane];
            sAtt[w * 64 + lane] = sattr[base + lane];
        }
        int t = 0;
        for (; t + 8 <= cnt; t += 8) {
#pragma unroll
            for (int u = 0; u < 4; u++) {
                int e = t + u * 2 + half;
                int s = sIdx[w * 64 + e];
                float ww = sAtt[w * 64 + e];
                bf16x8 v = *(const bf16x8*)(m + (size_t)s * DD + c8);
#pragma unroll
                for (int i = 0; i < 8; i++) acc[i] += (float)v[i] * ww;
            }
        }
        for (; t + 2 <= cnt; t += 2) {
            int e = t + half;
            int s = sIdx[w * 64 + e];
            float ww = sAtt[w * 64 + e];
            bf16x8 v = *(const bf16x8*)(m + (size_t)s * DD + c8);
#pragma unroll
            for (int i = 0; i < 8; i++) acc[i] += (float)v[i] * ww;
        }
        if (t < cnt && half == 0) {
            int s = sIdx[w * 64 + t];
            float ww = sAtt[w * 64 + t];
            bf16x8 v = *(const bf16x8*)(m + (size_t)s * DD + c8);
#pragma unroll
            for (int i = 0; i < 8; i++) acc[i] += (float)v[i] * ww;
        }
    }

#pragma unroll
    for (int i = 0; i < 8; i++) acc[i] += __shfl_xor(acc[i], 32, 64);

    if (half == 0) {
        bf16x8 o;
#pragma unroll
        for (int i = 0; i < 8; i++) o[i] = (__bf16)acc[i];
        *(bf16x8*)(aggb + (size_t)n * DD + c8) = o;
    }
}

// gru tile: 64 nodes x 32 cols, 6 gates; per-wave 32n x 16d (48 acc VGPRs)
// smraw: sA [2][64][32] 8KB @0, sB [6][32][32] 12KB @8192
__device__ __forceinline__ void gru_tile(int t, const __bf16* __restrict__ aggb,
                                         const __bf16* __restrict__ hbf,
                                         const float* __restrict__ hin,
                                         const __bf16* __restrict__ wih,
                                         const __bf16* __restrict__ whh,
                                         const float* __restrict__ b_ih,
                                         const float* __restrict__ b_hh,
                                         float* __restrict__ hout,
                                         __bf16* __restrict__ hbfout, char* smraw) {
    __bf16* sA = (__bf16*)smraw;
    __bf16* sB = (__bf16*)(smraw + 8192);
    int tid = threadIdx.x;
    int wave = tid >> 6, lane = tid & 63;
    int ln = lane & 15, quad = lane >> 4;
    int nodeBlock = (t >> 3) * 64;
    int colBlock = (t & 7) * 32;
    int nodeHalf = (wave >> 1) * 32;
    int colHalf = (wave & 1) * 16;
    int r4 = lane >> 2;
    int kb = (lane & 3) * 8;

    f32x4 acc[6][2] = {};   // [gate][nodeFrag]

    for (int k0 = 0; k0 < DD; k0 += 32) {
        __syncthreads();
        // 20 staging insts (A: 8, B: 12), 5 per wave
#pragma unroll
        for (int ii = 0; ii < 5; ii++) {
            int idx = wave * 5 + ii;
            const __bf16* src;
            __bf16* dst;
            if (idx < 8) {
                int s = idx >> 2;       // 0 = agg, 1 = h
                int rg = idx & 3;       // 16-row group
                const __bf16* A = s ? hbf : aggb;
                src = A + (size_t)(nodeBlock + rg * 16 + r4) * DD + k0 + kb;
                dst = sA + s * 2048 + rg * 512;
            } else {
                int j = idx - 8;        // 0..11
                int g6 = j >> 1;        // 0..5
                int rg = j & 1;         // 16-row group within 32
                const __bf16* B = (g6 < 3) ? wih : whh;
                int brow = (g6 % 3) * 256 + colBlock + rg * 16 + r4;
                src = B + (size_t)brow * DD + k0 + kb;
                dst = sB + g6 * 1024 + rg * 512;
            }
            gload_lds16(src, dst);
        }
        __syncthreads();

        bf16x8 aA[2], aH[2];
#pragma unroll
        for (int nf = 0; nf < 2; nf++) {
            aA[nf] = *(const bf16x8*)(sA + (nodeHalf + nf * 16 + ln) * 32 + quad * 8);
            aH[nf] = *(const bf16x8*)(sA + 2048 + (nodeHalf + nf * 16 + ln) * 32 + quad * 8);
        }
#pragma unroll
        for (int g = 0; g < 3; g++) {
            bf16x8 bI = *(const bf16x8*)(sB + g * 1024 + (colHalf + ln) * 32 + quad * 8);
            bf16x8 bH = *(const bf16x8*)(sB + (3 + g) * 1024 + (colHalf + ln) * 32 + quad * 8);
#pragma unroll
            for (int nf = 0; nf < 2; nf++) {
                acc[g][nf] = __builtin_amdgcn_mfma_f32_16x16x32_bf16(aA[nf], bI, acc[g][nf], 0, 0, 0);
                acc[3 + g][nf] = __builtin_amdgcn_mfma_f32_16x16x32_bf16(aH[nf], bH, acc[3 + g][nf], 0, 0, 0);
            }
        }
    }

#pragma unroll
    for (int nf = 0; nf < 2; nf++) {
#pragma unroll
        for (int r = 0; r < 4; r++) {
            int n = nodeBlock + nodeHalf + nf * 16 + quad * 4 + r;
            if (n >= NN) continue;
            int d = colBlock + colHalf + ln;
            float ir = acc[0][nf][r] + b_ih[d];
            float iz = acc[1][nf][r] + b_ih[d + 256];
            float in_ = acc[2][nf][r] + b_ih[d + 512];
            float hr = acc[3][nf][r] + b_hh[d];
            float hz = acc[4][nf][r] + b_hh[d + 256];
            float hn = acc[5][nf][r] + b_hh[d + 512];
            float rr = 1.f / (1.f + __expf(-(ir + hr)));
            float zz = 1.f / (1.f + __expf(-(iz + hz)));
            float ax = in_ + rr * hn;
            float e2 = __expf(-2.f * ax);
            float nnv = 2.f / (1.f + e2) - 1.f;
            float hp = hin[(size_t)n * DD + d];
            float o = (1.f - zz) * nnv + zz * hp;
            hout[(size_t)n * DD + d] = o;
            hbfout[(size_t)n * DD + d] = (__bf16)o;
        }
    }
}

// ---------------- persistent mega kernel: the whole 5-layer loop ----------------

__global__ __launch_bounds__(256, 2)
void ggnn_mega_k(const __bf16* __restrict__ wtb, const __bf16* __restrict__ wihb,
                 const __bf16* __restrict__ whhb, const float* __restrict__ b_ih,
                 const float* __restrict__ b_hh, const int* __restrict__ row_start,
                 const int* __restrict__ ssrc, const float* __restrict__ sattr,
                 float* __restrict__ hb, float* __restrict__ outp,
                 __bf16* __restrict__ hbfA, __bf16* __restrict__ hbfB,
                 __bf16* __restrict__ mb, __bf16* __restrict__ aggb,
                 int* __restrict__ bar) {
    __shared__ __align__(16) char smraw[20480];
    int bid = blockIdx.x, nb = gridDim.x;

    for (int l = 0; l < LL; l++) {
        const __bf16* hbfIn = (l & 1) ? hbfB : hbfA;
        __bf16* hbfOut = (l & 1) ? hbfA : hbfB;
        const float* hIn = (l & 1) ? outp : hb;
        float* hOut = (l & 1) ? hb : outp;
        const __bf16* wt = wtb + (size_t)l * DD * DD;

        for (int t = bid; t < 628; t += nb)
            gemm_tile(t, hbfIn, wt, mb, smraw);
        gbar(bar, nb);

        for (int g = bid; g < 2500; g += nb)
            agg_group(g, mb, row_start, ssrc, sattr, aggb, smraw);
        gbar(bar, nb);

        for (int t = bid; t < 1256; t += nb)
            gru_tile(t, aggb, hbfIn, hIn, wihb, whhb, b_ih, b_hh, hOut, hbfOut, smraw);
        if (l != LL - 1) gbar(bar, nb);
    }
    // l=4 writes outp = d_out
}

// ---------------- launch ----------------

extern "C" void kernel_launch(void* const* d_in, const int* in_sizes, int n_in,
                              void* d_out, int out_size, void* d_ws, size_t ws_size,
                              hipStream_t stream) {
    const float* x = (const float*)d_in[0];
    const int* edge_index = (const int*)d_in[1];
    const float* edge_attr = (const float*)d_in[2];
    const float* weight = (const float*)d_in[3];
    const float* w_ih = (const float*)d_in[4];
    const float* w_hh = (const float*)d_in[5];
    const float* b_ih = (const float*)d_in[6];
    const float* b_hh = (const float*)d_in[7];

    size_t off = 0;
    char* base = (char*)d_ws;
    auto carve = [&](size_t bytes) -> void* {
        void* p = base + off;
        off += (bytes + 255) & ~(size_t)255;
        return p;
    };
    float* hb = (float*)carve((size_t)NPAD * DD * 4);
    __bf16* hbfA = (__bf16*)carve((size_t)NPAD * DD * 2);
    __bf16* hbfB = (__bf16*)carve((size_t)NPAD * DD * 2);
    __bf16* mb = (__bf16*)carve((size_t)NPAD * DD * 2);
    __bf16* aggb = (__bf16*)carve((size_t)NPAD * DD * 2);
    __bf16* wtb = (__bf16*)carve((size_t)LL * DD * DD * 2);
    __bf16* wihb = (__bf16*)carve((size_t)768 * DD * 2);
    __bf16* whhb = (__bf16*)carve((size_t)768 * DD * 2);
    int* deg = (int*)carve((size_t)NN * 4);
    int* row_start = (int*)carve((size_t)(NN + 1) * 4);
    int* cursor = (int*)carve((size_t)NN * 4);
    int* ssrc = (int*)carve((size_t)EE * 4);
    float* sattr = (float*)carve((size_t)EE * 4);
    int* bar = (int*)carve(256);
    (void)ws_size;

    // setup (5 launches)
    transpose_wb_k<<<dim3(8, 8, LL), dim3(32, 8), 0, stream>>>(weight, wtb);
    prep_k<<<(NN * DD + 255) / 256, 256, 0, stream>>>(w_ih, w_hh, x, wihb, whhb,
                                                      hb, hbfA, hbfB, mb, aggb, deg, bar);
    hist_k<<<(EE + 255) / 256, 256, 0, stream>>>(edge_index + EE, deg);
    scan_k<<<1, 1024, 0, stream>>>(deg, row_start, cursor);
    fill_k<<<(EE + 255) / 256, 256, 0, stream>>>(edge_index, edge_attr, cursor, ssrc, sattr);

    // the 5-layer loop: one persistent kernel, regular launch (256 blocks <= 256 CUs)
    ggnn_mega_k<<<NBLK, 256, 0, stream>>>(wtb, wihb, whhb, b_ih, b_hh,
                                          row_start, ssrc, sattr,
                                          hb, (float*)d_out, hbfA, hbfB, mb, aggb, bar);
}

// Round 8
// 371.542 us; speedup vs baseline: 3.3208x; 3.3208x over previous
//
#include <hip/hip_runtime.h>
#include <hip/hip_bf16.h>

#define NN 10000
#define NPAD 10048   // 157 * 64
#define EE 320000
#define DD 256
#define LL 5

typedef __bf16 bf16x8 __attribute__((ext_vector_type(8)));
typedef float f32x4 __attribute__((ext_vector_type(4)));

__device__ __forceinline__ void gload_lds16(const void* g, void* l) {
    __builtin_amdgcn_global_load_lds(
        (const __attribute__((address_space(1))) void*)g,
        (__attribute__((address_space(3))) void*)l, 16, 0, 0);
}

// ---------------- setup kernels ----------------

// Wt[l][j][k] = W[l][k][j], bf16 (NT layout for m-GEMM)
__global__ void transpose_wb_k(const float* __restrict__ W, __bf16* __restrict__ Wt) {
    __shared__ float t[32][33];
    int l = blockIdx.z;
    int bx = blockIdx.x * 32;
    int by = blockIdx.y * 32;
    for (int i = threadIdx.y; i < 32; i += 8)
        t[i][threadIdx.x] = W[l * 65536 + (by + i) * DD + bx + threadIdx.x];
    __syncthreads();
    for (int i = threadIdx.y; i < 32; i += 8)
        Wt[l * 65536 + (bx + i) * DD + by + threadIdx.x] = (__bf16)t[threadIdx.x][i];
}

// merged elementwise prep: gru-weight conv, x conv, pad-zero, deg-zero
__global__ void prep_k(const float* __restrict__ w_ih, const float* __restrict__ w_hh,
                       const float* __restrict__ x,
                       __bf16* __restrict__ wihb, __bf16* __restrict__ whhb,
                       float* __restrict__ hb, __bf16* __restrict__ hbfA,
                       __bf16* __restrict__ hbfB, __bf16* __restrict__ mb,
                       __bf16* __restrict__ aggb, int* __restrict__ deg) {
    int i = blockIdx.x * blockDim.x + threadIdx.x;
    if (i < NN * DD) { float v = x[i]; hb[i] = v; hbfA[i] = (__bf16)v; }
    if (i < 768 * 256) { wihb[i] = (__bf16)w_ih[i]; whhb[i] = (__bf16)w_hh[i]; }
    if (i < (NPAD - NN) * DD) {
        hbfA[NN * DD + i] = (__bf16)0.f;
        hbfB[NN * DD + i] = (__bf16)0.f;
        mb[NN * DD + i] = (__bf16)0.f;
        aggb[NN * DD + i] = (__bf16)0.f;
    }
    if (i < NN) deg[i] = 0;
}

__global__ void hist_k(const int* __restrict__ dst, int* __restrict__ deg) {
    int e = blockIdx.x * blockDim.x + threadIdx.x;
    if (e < EE) atomicAdd(&deg[dst[e]], 1);
}

__global__ void scan_k(const int* __restrict__ deg, int* __restrict__ row_start,
                       int* __restrict__ cursor) {
    __shared__ int sums[1024];
    const int CH = 10;
    int t = threadIdx.x;
    int base = t * CH;
    int loc[CH];
    int s = 0;
#pragma unroll
    for (int i = 0; i < CH; i++) {
        int v = (base + i < NN) ? deg[base + i] : 0;
        loc[i] = s;
        s += v;
    }
    sums[t] = s;
    __syncthreads();
    for (int off = 1; off < 1024; off <<= 1) {
        int v = (t >= off) ? sums[t - off] : 0;
        __syncthreads();
        sums[t] += v;
        __syncthreads();
    }
    int pre = (t == 0) ? 0 : sums[t - 1];
#pragma unroll
    for (int i = 0; i < CH; i++) {
        int idx = base + i;
        if (idx < NN) {
            int v = pre + loc[i];
            row_start[idx] = v;
            cursor[idx] = v;
        }
    }
    if (t == 1023) row_start[NN] = sums[1023];
}

__global__ void fill_k(const int* __restrict__ ei, const float* __restrict__ attr,
                       int* __restrict__ cursor, int* __restrict__ ssrc,
                       float* __restrict__ sattr) {
    int e = blockIdx.x * blockDim.x + threadIdx.x;
    if (e < EE) {
        int dv = ei[EE + e];
        int p = atomicAdd(&cursor[dv], 1);
        ssrc[p] = ei[e];
        sattr[p] = attr[e];
    }
}

// ---------------- m = h @ W[l]  (LDS-staged MFMA, BK=64) ----------------
// block: 64 nodes x 64 cols, 4 waves (2x2); per 64-k chunk stage A 8KB + B 8KB
// LDS layout: [sub(2)][64][32] per matrix (two 32-k halves) — conflict-free rows

__global__ __launch_bounds__(256, 2)
void gemm_m_k(const __bf16* __restrict__ hbf, const __bf16* __restrict__ wt,
              __bf16* __restrict__ mout) {
    __shared__ __bf16 sA[2][64][32];
    __shared__ __bf16 sB[2][64][32];
    int tid = threadIdx.x;
    int wave = tid >> 6, lane = tid & 63;
    int ln = lane & 15, quad = lane >> 4;
    int rowBlock = blockIdx.x * 64;
    int colBlock = blockIdx.y * 64;
    int rowHalf = (wave >> 1) * 32;
    int colHalf = (wave & 1) * 32;
    int r4 = lane >> 2;        // 0..15
    int kb = (lane & 3) * 8;   // 8-elem offset within 32-k half

    f32x4 acc[2][2] = {};

    for (int k0 = 0; k0 < DD; k0 += 64) {
        __syncthreads();
        // 16 wave-insts total: idx = wave*4+ii; idx<8 -> A, else B
#pragma unroll
        for (int ii = 0; ii < 4; ii++) {
            int idx = wave * 4 + ii;
            int mat = idx >> 3;        // 0 = A, 1 = B
            int rem = idx & 7;
            int sub = rem >> 2;        // k half
            int rg = rem & 3;          // 16-row group
            const __bf16* src;
            __bf16* dst;
            if (mat == 0) {
                src = hbf + (size_t)(rowBlock + rg * 16 + r4) * DD + k0 + sub * 32 + kb;
                dst = &sA[sub][rg * 16][0];
            } else {
                src = wt + (size_t)(colBlock + rg * 16 + r4) * DD + k0 + sub * 32 + kb;
                dst = &sB[sub][rg * 16][0];
            }
            gload_lds16(src, dst);
        }
        __syncthreads();

#pragma unroll
        for (int sub = 0; sub < 2; sub++) {
            bf16x8 af[2], bf[2];
#pragma unroll
            for (int i = 0; i < 2; i++)
                af[i] = *(const bf16x8*)&sA[sub][rowHalf + i * 16 + ln][quad * 8];
#pragma unroll
            for (int cc = 0; cc < 2; cc++)
                bf[cc] = *(const bf16x8*)&sB[sub][colHalf + cc * 16 + ln][quad * 8];
#pragma unroll
            for (int nf = 0; nf < 2; nf++)
#pragma unroll
                for (int cc = 0; cc < 2; cc++)
                    acc[nf][cc] = __builtin_amdgcn_mfma_f32_16x16x32_bf16(af[nf], bf[cc], acc[nf][cc], 0, 0, 0);
        }
    }
#pragma unroll
    for (int nf = 0; nf < 2; nf++)
#pragma unroll
        for (int r = 0; r < 4; r++) {
            int n = rowBlock + rowHalf + nf * 16 + quad * 4 + r;
#pragma unroll
            for (int cc = 0; cc < 2; cc++) {
                int d = colBlock + colHalf + cc * 16 + ln;
                mout[(size_t)n * DD + d] = (__bf16)acc[nf][cc][r];
            }
        }
}

// ---------------- aggregation: agg[n,:] = sum_{e: dst=n} m[src_e,:]*attr_e ----------------
// wave per node; LDS-staged edge lists; 2 edges per bf16x8 gather; shfl_xor(32) combine

__global__ __launch_bounds__(256)
void aggregate_bf_k(const __bf16* __restrict__ m, const int* __restrict__ row_start,
                    const int* __restrict__ ssrc, const float* __restrict__ sattr,
                    __bf16* __restrict__ aggb) {
    __shared__ int sIdx[4][64];
    __shared__ float sAtt[4][64];
    int w = threadIdx.x >> 6, lane = threadIdx.x & 63;
    int n = blockIdx.x * 4 + w;
    int s0 = row_start[n], s1 = row_start[n + 1];
    int half = lane >> 5;
    int c8 = (lane & 31) * 8;

    float acc[8] = {0.f, 0.f, 0.f, 0.f, 0.f, 0.f, 0.f, 0.f};

    for (int base = s0; base < s1; base += 64) {
        int cnt = min(64, s1 - base);
        if (lane < cnt) {
            sIdx[w][lane] = ssrc[base + lane];
            sAtt[w][lane] = sattr[base + lane];
        }
        int t = 0;
        for (; t + 8 <= cnt; t += 8) {
#pragma unroll
            for (int u = 0; u < 4; u++) {
                int e = t + u * 2 + half;
                int s = sIdx[w][e];
                float ww = sAtt[w][e];
                bf16x8 v = *(const bf16x8*)(m + (size_t)s * DD + c8);
#pragma unroll
                for (int i = 0; i < 8; i++) acc[i] += (float)v[i] * ww;
            }
        }
        for (; t + 2 <= cnt; t += 2) {
            int e = t + half;
            int s = sIdx[w][e];
            float ww = sAtt[w][e];
            bf16x8 v = *(const bf16x8*)(m + (size_t)s * DD + c8);
#pragma unroll
            for (int i = 0; i < 8; i++) acc[i] += (float)v[i] * ww;
        }
        if (t < cnt && half == 0) {
            int s = sIdx[w][t];
            float ww = sAtt[w][t];
            bf16x8 v = *(const bf16x8*)(m + (size_t)s * DD + c8);
#pragma unroll
            for (int i = 0; i < 8; i++) acc[i] += (float)v[i] * ww;
        }
    }

#pragma unroll
    for (int i = 0; i < 8; i++) acc[i] += __shfl_xor(acc[i], 32, 64);

    if (half == 0) {
        bf16x8 o;
#pragma unroll
        for (int i = 0; i < 8; i++) o[i] = (__bf16)acc[i];
        *(bf16x8*)(aggb + (size_t)n * DD + c8) = o;
    }
}

// ---------------- fused GRU: LDS-staged 6-gate MFMA + gate math (BK=32) ----------------
// block: 64 nodes x 64 d-cols, 4 waves (2x2); wave: 32n x 32d x 6 gates

__global__ __launch_bounds__(256, 2)
void gru_mfma_k(const __bf16* __restrict__ aggb, const __bf16* __restrict__ hbf,
                const float* __restrict__ hin,
                const __bf16* __restrict__ wih, const __bf16* __restrict__ whh,
                const float* __restrict__ b_ih, const float* __restrict__ b_hh,
                float* __restrict__ hout, __bf16* __restrict__ hbfout) {
    __shared__ __bf16 sA[2][64][32];
    __shared__ __bf16 sB[6][64][32];
    int tid = threadIdx.x;
    int wave = tid >> 6, lane = tid & 63;
    int ln = lane & 15, quad = lane >> 4;
    int nodeBlock = blockIdx.x * 64;
    int colBlock = blockIdx.y * 64;
    int nodeHalf = (wave >> 1) * 32;
    int colHalf = (wave & 1) * 32;
    int r4 = lane >> 2;
    int kb = (lane & 3) * 8;

    f32x4 acc[6][2][2] = {};

    for (int k0 = 0; k0 < DD; k0 += 32) {
        __syncthreads();
#pragma unroll
        for (int ii = 0; ii < 8; ii++) {
            int idx = wave * 8 + ii;
            const __bf16* src;
            __bf16* dst;
            if (idx < 8) {
                int s = idx >> 2;
                int rg = idx & 3;
                const __bf16* A = s ? hbf : aggb;
                src = A + (size_t)(nodeBlock + rg * 16 + r4) * DD + k0 + kb;
                dst = &sA[s][rg * 16][0];
            } else {
                int j = idx - 8;
                int g6 = j >> 2;
                int rg = j & 3;
                const __bf16* B = (g6 < 3) ? wih : whh;
                int brow = (g6 % 3) * 256 + colBlock + rg * 16 + r4;
                src = B + (size_t)brow * DD + k0 + kb;
                dst = &sB[g6][rg * 16][0];
            }
            gload_lds16(src, dst);
        }
        __syncthreads();

        bf16x8 aA[2], aH[2];
#pragma unroll
        for (int nf = 0; nf < 2; nf++) {
            aA[nf] = *(const bf16x8*)&sA[0][nodeHalf + nf * 16 + ln][quad * 8];
            aH[nf] = *(const bf16x8*)&sA[1][nodeHalf + nf * 16 + ln][quad * 8];
        }
#pragma unroll
        for (int g = 0; g < 3; g++) {
#pragma unroll
            for (int cc = 0; cc < 2; cc++) {
                bf16x8 bI = *(const bf16x8*)&sB[g][colHalf + cc * 16 + ln][quad * 8];
                bf16x8 bH = *(const bf16x8*)&sB[3 + g][colHalf + cc * 16 + ln][quad * 8];
#pragma unroll
                for (int nf = 0; nf < 2; nf++) {
                    acc[g][nf][cc] = __builtin_amdgcn_mfma_f32_16x16x32_bf16(aA[nf], bI, acc[g][nf][cc], 0, 0, 0);
                    acc[3 + g][nf][cc] = __builtin_amdgcn_mfma_f32_16x16x32_bf16(aH[nf], bH, acc[3 + g][nf][cc], 0, 0, 0);
                }
            }
        }
    }

    // epilogue
#pragma unroll
    for (int nf = 0; nf < 2; nf++) {
#pragma unroll
        for (int r = 0; r < 4; r++) {
            int n = nodeBlock + nodeHalf + nf * 16 + quad * 4 + r;
            if (n >= NN) continue;
#pragma unroll
            for (int cc = 0; cc < 2; cc++) {
                int d = colBlock + colHalf + cc * 16 + ln;
                float ir = acc[0][nf][cc][r] + b_ih[d];
                float iz = acc[1][nf][cc][r] + b_ih[d + 256];
                float in_ = acc[2][nf][cc][r] + b_ih[d + 512];
                float hr = acc[3][nf][cc][r] + b_hh[d];
                float hz = acc[4][nf][cc][r] + b_hh[d + 256];
                float hn = acc[5][nf][cc][r] + b_hh[d + 512];
                float rr = 1.f / (1.f + __expf(-(ir + hr)));
                float zz = 1.f / (1.f + __expf(-(iz + hz)));
                float ax = in_ + rr * hn;
                float e2 = __expf(-2.f * ax);
                float nnv = 2.f / (1.f + e2) - 1.f;
                float hp = hin[(size_t)n * DD + d];
                float o = (1.f - zz) * nnv + zz * hp;
                hout[(size_t)n * DD + d] = o;
                hbfout[(size_t)n * DD + d] = (__bf16)o;
            }
        }
    }
}

// ---------------- launch ----------------

extern "C" void kernel_launch(void* const* d_in, const int* in_sizes, int n_in,
                              void* d_out, int out_size, void* d_ws, size_t ws_size,
                              hipStream_t stream) {
    const float* x = (const float*)d_in[0];
    const int* edge_index = (const int*)d_in[1];
    const float* edge_attr = (const float*)d_in[2];
    const float* weight = (const float*)d_in[3];
    const float* w_ih = (const float*)d_in[4];
    const float* w_hh = (const float*)d_in[5];
    const float* b_ih = (const float*)d_in[6];
    const float* b_hh = (const float*)d_in[7];

    size_t off = 0;
    char* base = (char*)d_ws;
    auto carve = [&](size_t bytes) -> void* {
        void* p = base + off;
        off += (bytes + 255) & ~(size_t)255;
        return p;
    };
    float* hb = (float*)carve((size_t)NPAD * DD * 4);
    __bf16* hbfA = (__bf16*)carve((size_t)NPAD * DD * 2);
    __bf16* hbfB = (__bf16*)carve((size_t)NPAD * DD * 2);
    __bf16* mb = (__bf16*)carve((size_t)NPAD * DD * 2);
    __bf16* aggb = (__bf16*)carve((size_t)NPAD * DD * 2);
    __bf16* wtb = (__bf16*)carve((size_t)LL * DD * DD * 2);
    __bf16* wihb = (__bf16*)carve((size_t)768 * DD * 2);
    __bf16* whhb = (__bf16*)carve((size_t)768 * DD * 2);
    int* deg = (int*)carve((size_t)NN * 4);
    int* row_start = (int*)carve((size_t)(NN + 1) * 4);
    int* cursor = (int*)carve((size_t)NN * 4);
    int* ssrc = (int*)carve((size_t)EE * 4);
    float* sattr = (float*)carve((size_t)EE * 4);
    (void)ws_size;

    // setup (5 launches)
    transpose_wb_k<<<dim3(8, 8, LL), dim3(32, 8), 0, stream>>>(weight, wtb);
    prep_k<<<(NN * DD + 255) / 256, 256, 0, stream>>>(w_ih, w_hh, x, wihb, whhb,
                                                      hb, hbfA, hbfB, mb, aggb, deg);
    hist_k<<<(EE + 255) / 256, 256, 0, stream>>>(edge_index + EE, deg);
    scan_k<<<1, 1024, 0, stream>>>(deg, row_start, cursor);
    fill_k<<<(EE + 255) / 256, 256, 0, stream>>>(edge_index, edge_attr, cursor, ssrc, sattr);

    float* hA = hb;
    float* hB = (float*)d_out;
    __bf16* hbfIn = hbfA;
    __bf16* hbfOut = hbfB;
    for (int l = 0; l < LL; l++) {
        gemm_m_k<<<dim3(157, 4), 256, 0, stream>>>(hbfIn, wtb + (size_t)l * DD * DD, mb);
        aggregate_bf_k<<<2500, 256, 0, stream>>>(mb, row_start, ssrc, sattr, aggb);
        gru_mfma_k<<<dim3(157, 4), 256, 0, stream>>>(aggb, hbfIn, hA, wihb, whhb,
                                                     b_ih, b_hh, hB, hbfOut);
        float* t = hA; hA = hB; hB = t;
        __bf16* tb = hbfIn; hbfIn = hbfOut; hbfOut = tb;
    }
    // 5 swaps: final h landed in d_out
}

// Round 9
// 352.100 us; speedup vs baseline: 3.5041x; 1.0552x over previous
//
#include <hip/hip_runtime.h>
#include <hip/hip_bf16.h>

#define NN 10000
#define NPAD 10048   // 157 * 64
#define EE 320000
#define DD 256
#define LL 5

typedef __bf16 bf16x8 __attribute__((ext_vector_type(8)));
typedef __bf16 bf16x4 __attribute__((ext_vector_type(4)));
typedef float f32x4 __attribute__((ext_vector_type(4)));

__device__ __forceinline__ void gload_lds16(const void* g, void* l) {
    __builtin_amdgcn_global_load_lds(
        (const __attribute__((address_space(1))) void*)g,
        (__attribute__((address_space(3))) void*)l, 16, 0, 0);
}

// ---------------- setup kernels ----------------

// merged elementwise prep: whh conv, x conv, pad-zero, deg-zero
__global__ void prep_k(const float* __restrict__ w_hh, const float* __restrict__ x,
                       __bf16* __restrict__ whhb,
                       float* __restrict__ hb, __bf16* __restrict__ hbfA,
                       __bf16* __restrict__ hbfB, __bf16* __restrict__ aggb,
                       int* __restrict__ deg) {
    int i = blockIdx.x * blockDim.x + threadIdx.x;
    if (i < NN * DD) { float v = x[i]; hb[i] = v; hbfA[i] = (__bf16)v; }
    if (i < 768 * 256) whhb[i] = (__bf16)w_hh[i];
    if (i < (NPAD - NN) * DD) {
        hbfA[NN * DD + i] = (__bf16)0.f;
        hbfB[NN * DD + i] = (__bf16)0.f;
        aggb[NN * DD + i] = (__bf16)0.f;
    }
    if (i < NN) deg[i] = 0;
}

__global__ void hist_k(const int* __restrict__ dst, int* __restrict__ deg) {
    int e = blockIdx.x * blockDim.x + threadIdx.x;
    if (e < EE) atomicAdd(&deg[dst[e]], 1);
}

__global__ void scan_k(const int* __restrict__ deg, int* __restrict__ row_start,
                       int* __restrict__ cursor) {
    __shared__ int sums[1024];
    const int CH = 10;
    int t = threadIdx.x;
    int base = t * CH;
    int loc[CH];
    int s = 0;
#pragma unroll
    for (int i = 0; i < CH; i++) {
        int v = (base + i < NN) ? deg[base + i] : 0;
        loc[i] = s;
        s += v;
    }
    sums[t] = s;
    __syncthreads();
    for (int off = 1; off < 1024; off <<= 1) {
        int v = (t >= off) ? sums[t - off] : 0;
        __syncthreads();
        sums[t] += v;
        __syncthreads();
    }
    int pre = (t == 0) ? 0 : sums[t - 1];
#pragma unroll
    for (int i = 0; i < CH; i++) {
        int idx = base + i;
        if (idx < NN) {
            int v = pre + loc[i];
            row_start[idx] = v;
            cursor[idx] = v;
        }
    }
    if (t == 1023) row_start[NN] = sums[1023];
}

__global__ void fill_k(const int* __restrict__ ei, const float* __restrict__ attr,
                       int* __restrict__ cursor, int* __restrict__ ssrc,
                       float* __restrict__ sattr) {
    int e = blockIdx.x * blockDim.x + threadIdx.x;
    if (e < EE) {
        int dv = ei[EE + e];
        int p = atomicAdd(&cursor[dv], 1);
        ssrc[p] = ei[e];
        sattr[p] = attr[e];
    }
}

// ---------------- beff[l][j][t] = sum_d w_ih[j][d] * W[l][t][d], PURE FP32, ----------------
// single rounding to bf16 at the end. [768x256]x[256x256] NT per layer; grid (12,4,L).

__global__ __launch_bounds__(256)
void beff32_k(const float* __restrict__ wih, const float* __restrict__ W,
              __bf16* __restrict__ beff) {
    __shared__ float As[16][68];
    __shared__ float Bs[16][68];
    int l = blockIdx.z;
    const float* Wl = W + (size_t)l * DD * DD;
    __bf16* Cl = beff + (size_t)l * 768 * DD;
    int tid = threadIdx.x;
    int tx = tid & 15, ty = tid >> 4;
    int jBase = blockIdx.x * 64;
    int tBase = blockIdx.y * 64;
    int lr = tid >> 2, lq = tid & 3;
    float acc[4][4];
#pragma unroll
    for (int i = 0; i < 4; i++)
#pragma unroll
        for (int j = 0; j < 4; j++) acc[i][j] = 0.f;

    for (int k0 = 0; k0 < DD; k0 += 16) {
        float4 av = *(const float4*)(wih + (size_t)(jBase + lr) * DD + k0 + lq * 4);
        float4 bv = *(const float4*)(Wl + (size_t)(tBase + lr) * DD + k0 + lq * 4);
        __syncthreads();
        As[lq * 4 + 0][lr] = av.x; As[lq * 4 + 1][lr] = av.y;
        As[lq * 4 + 2][lr] = av.z; As[lq * 4 + 3][lr] = av.w;
        Bs[lq * 4 + 0][lr] = bv.x; Bs[lq * 4 + 1][lr] = bv.y;
        Bs[lq * 4 + 2][lr] = bv.z; Bs[lq * 4 + 3][lr] = bv.w;
        __syncthreads();
#pragma unroll
        for (int kk = 0; kk < 16; kk++) {
            float a0 = As[kk][ty * 4 + 0], a1 = As[kk][ty * 4 + 1];
            float a2 = As[kk][ty * 4 + 2], a3 = As[kk][ty * 4 + 3];
            float b0 = Bs[kk][tx * 4 + 0], b1 = Bs[kk][tx * 4 + 1];
            float b2 = Bs[kk][tx * 4 + 2], b3 = Bs[kk][tx * 4 + 3];
            acc[0][0] += a0 * b0; acc[0][1] += a0 * b1; acc[0][2] += a0 * b2; acc[0][3] += a0 * b3;
            acc[1][0] += a1 * b0; acc[1][1] += a1 * b1; acc[1][2] += a1 * b2; acc[1][3] += a1 * b3;
            acc[2][0] += a2 * b0; acc[2][1] += a2 * b1; acc[2][2] += a2 * b2; acc[2][3] += a2 * b3;
            acc[3][0] += a3 * b0; acc[3][1] += a3 * b1; acc[3][2] += a3 * b2; acc[3][3] += a3 * b3;
        }
    }
#pragma unroll
    for (int i = 0; i < 4; i++) {
        int j = jBase + ty * 4 + i;
        bf16x4 o;
        o[0] = (__bf16)acc[i][0]; o[1] = (__bf16)acc[i][1];
        o[2] = (__bf16)acc[i][2]; o[3] = (__bf16)acc[i][3];
        *(bf16x4*)(Cl + (size_t)j * DD + tBase + tx * 4) = o;
    }
}

// ---------------- aggregation: aggr_raw[n,:] = sum_{e: dst=n} h[src_e,:]*attr_e ----------------
// wave per node; LDS-staged edge lists; 2 edges per bf16x8 gather; shfl_xor(32) combine

__global__ __launch_bounds__(256)
void aggregate_bf_k(const __bf16* __restrict__ hsrc, const int* __restrict__ row_start,
                    const int* __restrict__ ssrc, const float* __restrict__ sattr,
                    __bf16* __restrict__ aggb) {
    __shared__ int sIdx[4][64];
    __shared__ float sAtt[4][64];
    int w = threadIdx.x >> 6, lane = threadIdx.x & 63;
    int n = blockIdx.x * 4 + w;
    int s0 = row_start[n], s1 = row_start[n + 1];
    int half = lane >> 5;
    int c8 = (lane & 31) * 8;

    float acc[8] = {0.f, 0.f, 0.f, 0.f, 0.f, 0.f, 0.f, 0.f};

    for (int base = s0; base < s1; base += 64) {
        int cnt = min(64, s1 - base);
        if (lane < cnt) {
            sIdx[w][lane] = ssrc[base + lane];
            sAtt[w][lane] = sattr[base + lane];
        }
        int t = 0;
        for (; t + 8 <= cnt; t += 8) {
#pragma unroll
            for (int u = 0; u < 4; u++) {
                int e = t + u * 2 + half;
                int s = sIdx[w][e];
                float ww = sAtt[w][e];
                bf16x8 v = *(const bf16x8*)(hsrc + (size_t)s * DD + c8);
#pragma unroll
                for (int i = 0; i < 8; i++) acc[i] += (float)v[i] * ww;
            }
        }
        for (; t + 2 <= cnt; t += 2) {
            int e = t + half;
            int s = sIdx[w][e];
            float ww = sAtt[w][e];
            bf16x8 v = *(const bf16x8*)(hsrc + (size_t)s * DD + c8);
#pragma unroll
            for (int i = 0; i < 8; i++) acc[i] += (float)v[i] * ww;
        }
        if (t < cnt && half == 0) {
            int s = sIdx[w][t];
            float ww = sAtt[w][t];
            bf16x8 v = *(const bf16x8*)(hsrc + (size_t)s * DD + c8);
#pragma unroll
            for (int i = 0; i < 8; i++) acc[i] += (float)v[i] * ww;
        }
    }

#pragma unroll
    for (int i = 0; i < 8; i++) acc[i] += __shfl_xor(acc[i], 32, 64);

    if (half == 0) {
        bf16x8 o;
#pragma unroll
        for (int i = 0; i < 8; i++) o[i] = (__bf16)acc[i];
        *(bf16x8*)(aggb + (size_t)n * DD + c8) = o;
    }
}

// ---------------- fused GRU: LDS-staged 6-gate MFMA + gate math (BK=32) ----------------
// i-gates use beff (= w_ih composed with W in fp32); h-gates use whh.
// block: 64 nodes x 64 d-cols, 4 waves (2x2); wave: 32n x 32d x 6 gates

__global__ __launch_bounds__(256, 2)
void gru_mfma_k(const __bf16* __restrict__ aggb, const __bf16* __restrict__ hbf,
                const float* __restrict__ hin,
                const __bf16* __restrict__ bihw, const __bf16* __restrict__ whh,
                const float* __restrict__ b_ih, const float* __restrict__ b_hh,
                float* __restrict__ hout, __bf16* __restrict__ hbfout) {
    __shared__ __bf16 sA[2][64][32];
    __shared__ __bf16 sB[6][64][32];
    int tid = threadIdx.x;
    int wave = tid >> 6, lane = tid & 63;
    int ln = lane & 15, quad = lane >> 4;
    int nodeBlock = blockIdx.x * 64;
    int colBlock = blockIdx.y * 64;
    int nodeHalf = (wave >> 1) * 32;
    int colHalf = (wave & 1) * 32;
    int r4 = lane >> 2;
    int kb = (lane & 3) * 8;

    f32x4 acc[6][2][2] = {};

    for (int k0 = 0; k0 < DD; k0 += 32) {
        __syncthreads();
#pragma unroll
        for (int ii = 0; ii < 8; ii++) {
            int idx = wave * 8 + ii;
            const __bf16* src;
            __bf16* dst;
            if (idx < 8) {
                int s = idx >> 2;
                int rg = idx & 3;
                const __bf16* A = s ? hbf : aggb;
                src = A + (size_t)(nodeBlock + rg * 16 + r4) * DD + k0 + kb;
                dst = &sA[s][rg * 16][0];
            } else {
                int j = idx - 8;
                int g6 = j >> 2;
                int rg = j & 3;
                const __bf16* B = (g6 < 3) ? bihw : whh;
                int brow = (g6 % 3) * 256 + colBlock + rg * 16 + r4;
                src = B + (size_t)brow * DD + k0 + kb;
                dst = &sB[g6][rg * 16][0];
            }
            gload_lds16(src, dst);
        }
        __syncthreads();

        bf16x8 aA[2], aH[2];
#pragma unroll
        for (int nf = 0; nf < 2; nf++) {
            aA[nf] = *(const bf16x8*)&sA[0][nodeHalf + nf * 16 + ln][quad * 8];
            aH[nf] = *(const bf16x8*)&sA[1][nodeHalf + nf * 16 + ln][quad * 8];
        }
#pragma unroll
        for (int g = 0; g < 3; g++) {
#pragma unroll
            for (int cc = 0; cc < 2; cc++) {
                bf16x8 bI = *(const bf16x8*)&sB[g][colHalf + cc * 16 + ln][quad * 8];
                bf16x8 bH = *(const bf16x8*)&sB[3 + g][colHalf + cc * 16 + ln][quad * 8];
#pragma unroll
                for (int nf = 0; nf < 2; nf++) {
                    acc[g][nf][cc] = __builtin_amdgcn_mfma_f32_16x16x32_bf16(aA[nf], bI, acc[g][nf][cc], 0, 0, 0);
                    acc[3 + g][nf][cc] = __builtin_amdgcn_mfma_f32_16x16x32_bf16(aH[nf], bH, acc[3 + g][nf][cc], 0, 0, 0);
                }
            }
        }
    }

    // epilogue
#pragma unroll
    for (int nf = 0; nf < 2; nf++) {
#pragma unroll
        for (int r = 0; r < 4; r++) {
            int n = nodeBlock + nodeHalf + nf * 16 + quad * 4 + r;
            if (n >= NN) continue;
#pragma unroll
            for (int cc = 0; cc < 2; cc++) {
                int d = colBlock + colHalf + cc * 16 + ln;
                float ir = acc[0][nf][cc][r] + b_ih[d];
                float iz = acc[1][nf][cc][r] + b_ih[d + 256];
                float in_ = acc[2][nf][cc][r] + b_ih[d + 512];
                float hr = acc[3][nf][cc][r] + b_hh[d];
                float hz = acc[4][nf][cc][r] + b_hh[d + 256];
                float hn = acc[5][nf][cc][r] + b_hh[d + 512];
                float rr = 1.f / (1.f + __expf(-(ir + hr)));
                float zz = 1.f / (1.f + __expf(-(iz + hz)));
                float ax = in_ + rr * hn;
                float e2 = __expf(-2.f * ax);
                float nnv = 2.f / (1.f + e2) - 1.f;
                float hp = hin[(size_t)n * DD + d];
                float o = (1.f - zz) * nnv + zz * hp;
                hout[(size_t)n * DD + d] = o;
                hbfout[(size_t)n * DD + d] = (__bf16)o;
            }
        }
    }
}

// ---------------- launch ----------------

extern "C" void kernel_launch(void* const* d_in, const int* in_sizes, int n_in,
                              void* d_out, int out_size, void* d_ws, size_t ws_size,
                              hipStream_t stream) {
    const float* x = (const float*)d_in[0];
    const int* edge_index = (const int*)d_in[1];
    const float* edge_attr = (const float*)d_in[2];
    const float* weight = (const float*)d_in[3];
    const float* w_ih = (const float*)d_in[4];
    const float* w_hh = (const float*)d_in[5];
    const float* b_ih = (const float*)d_in[6];
    const float* b_hh = (const float*)d_in[7];

    size_t off = 0;
    char* base = (char*)d_ws;
    auto carve = [&](size_t bytes) -> void* {
        void* p = base + off;
        off += (bytes + 255) & ~(size_t)255;
        return p;
    };
    float* hb = (float*)carve((size_t)NPAD * DD * 4);
    __bf16* hbfA = (__bf16*)carve((size_t)NPAD * DD * 2);
    __bf16* hbfB = (__bf16*)carve((size_t)NPAD * DD * 2);
    __bf16* aggb = (__bf16*)carve((size_t)NPAD * DD * 2);
    __bf16* whhb = (__bf16*)carve((size_t)768 * DD * 2);
    __bf16* beff = (__bf16*)carve((size_t)LL * 768 * DD * 2);
    int* deg = (int*)carve((size_t)NN * 4);
    int* row_start = (int*)carve((size_t)(NN + 1) * 4);
    int* cursor = (int*)carve((size_t)NN * 4);
    int* ssrc = (int*)carve((size_t)EE * 4);
    float* sattr = (float*)carve((size_t)EE * 4);
    (void)ws_size;

    // setup (5 launches)
    prep_k<<<(NN * DD + 255) / 256, 256, 0, stream>>>(w_hh, x, whhb, hb, hbfA, hbfB,
                                                      aggb, deg);
    hist_k<<<(EE + 255) / 256, 256, 0, stream>>>(edge_index + EE, deg);
    scan_k<<<1, 1024, 0, stream>>>(deg, row_start, cursor);
    fill_k<<<(EE + 255) / 256, 256, 0, stream>>>(edge_index, edge_attr, cursor, ssrc, sattr);
    beff32_k<<<dim3(12, 4, LL), 256, 0, stream>>>(w_ih, weight, beff);

    float* hA = hb;
    float* hB = (float*)d_out;
    __bf16* hbfIn = hbfA;
    __bf16* hbfOut = hbfB;
    for (int l = 0; l < LL; l++) {
        aggregate_bf_k<<<2500, 256, 0, stream>>>(hbfIn, row_start, ssrc, sattr, aggb);
        gru_mfma_k<<<dim3(157, 4), 256, 0, stream>>>(aggb, hbfIn, hA,
                                                     beff + (size_t)l * 768 * DD, whhb,
                                                     b_ih, b_hh, hB, hbfOut);
        float* t = hA; hA = hB; hB = t;
        __bf16* tb = hbfIn; hbfIn = hbfOut; hbfOut = tb;
    }
    // 5 swaps: final h landed in d_out
}